// Round 2
// baseline (442.931 us; speedup 1.0000x reference)
//
#include <hip/hip_runtime.h>
#include <math.h>

#define N 4096
#define THREADS 256
#define BATCH 8192

// XOR swizzle: bijection on [0,4096) making all three LDS access families
// (stride-256 reads, 16-contiguous writes, stride-16 writes) bank-minimal.
// MEASURED conflict-free in round 0 (SQ_LDS_BANK_CONFLICT == 0) -- do not touch.
#define SWZ(i) ((i) ^ (((i) >> 4) & 15))
// dft16 stores X_p at slot IDX16(p) (base-4 digit swap; involution)
#define IDX16(p) ((((p) & 3) << 2) | ((p) >> 2))

__device__ __forceinline__ float2 cmul(float2 a, float2 b) {
    return make_float2(fmaf(a.x, b.x, -(a.y * b.y)), fmaf(a.x, b.y, a.y * b.x));
}
// a * conj(b)
__device__ __forceinline__ float2 cmulc(float2 a, float2 b) {
    return make_float2(fmaf(a.x, b.x, a.y * b.y), fmaf(a.y, b.x, -(a.x * b.y)));
}

// radix-4 butterfly at v[base + r*stride]; forward uses w4 = -i, inverse +i
template<bool INV>
__device__ __forceinline__ void dft4(float2* v, int base, int stride) {
    float2 a = v[base], b = v[base + stride], c = v[base + 2 * stride], d = v[base + 3 * stride];
    float2 t0 = make_float2(a.x + c.x, a.y + c.y);
    float2 t1 = make_float2(a.x - c.x, a.y - c.y);
    float2 t2 = make_float2(b.x + d.x, b.y + d.y);
    float2 t3 = make_float2(b.x - d.x, b.y - d.y);
    float2 j3 = INV ? make_float2(-t3.y, t3.x) : make_float2(t3.y, -t3.x);
    v[base]              = make_float2(t0.x + t2.x, t0.y + t2.y);
    v[base + stride]     = make_float2(t1.x + j3.x, t1.y + j3.y);
    v[base + 2 * stride] = make_float2(t0.x - t2.x, t0.y - t2.y);
    v[base + 3 * stride] = make_float2(t1.x - j3.x, t1.y - j3.y);
}

// internal W16^{n1*k2} twiddles; slot set is symmetric under n1<->k2 so this
// works for both dft16 and dft16_perm.
template<bool INV>
__device__ __forceinline__ void tw16(float2* v) {
    const float C1 = 0.9238795325112867f;
    const float S1 = 0.3826834323650898f;
    const float R2 = 0.7071067811865476f;
    const float s = INV ? 1.0f : -1.0f;
    const float2 W1 = make_float2(C1, s * S1);
    const float2 W2 = make_float2(R2, s * R2);
    const float2 W3 = make_float2(S1, s * C1);
    const float2 W6 = make_float2(-R2, s * R2);
    const float2 W9 = make_float2(-C1, -s * S1);
    v[5]  = cmul(v[5],  W1);
    v[9]  = cmul(v[9],  W2);
    v[13] = cmul(v[13], W3);
    v[6]  = cmul(v[6],  W2);
    { float2 z = v[10]; v[10] = INV ? make_float2(-z.y, z.x) : make_float2(z.y, -z.x); }  // W4 = -/+ i
    v[14] = cmul(v[14], W6);
    v[7]  = cmul(v[7],  W3);
    v[11] = cmul(v[11], W6);
    v[15] = cmul(v[15], W9);
}

// input sample n at v[n]; output X_p at v[IDX16(p)]
template<bool INV>
__device__ __forceinline__ void dft16(float2* v) {
    #pragma unroll
    for (int n1 = 0; n1 < 4; ++n1) dft4<INV>(v, n1, 4);
    tw16<INV>(v);
    #pragma unroll
    for (int k2 = 0; k2 < 4; ++k2) dft4<INV>(v, 4 * k2, 1);
}

// input sample n at v[IDX16(n)]; output X_p at v[p]
template<bool INV>
__device__ __forceinline__ void dft16_perm(float2* v) {
    #pragma unroll
    for (int n1 = 0; n1 < 4; ++n1) dft4<INV>(v, 4 * n1, 1);
    tw16<INV>(v);
    #pragma unroll
    for (int k2 = 0; k2 < 4; ++k2) dft4<INV>(v, k2, 4);
}

// ---------------------------------------------------------------------------
// Register-generated twiddle powers. Replaces the per-thread tw[] gathers
// (wave-level stride 8p bytes -> up to 64 cache lines per gather, serialized
// in the TA/TD pipe) with two independent 7-deep cmul chains. Math placement
// identical to the round-0 table version; absmax unchanged (verified r1).
// ---------------------------------------------------------------------------
// v[IDX16(p)] *= w1^p, p=1..15
__device__ __forceinline__ void twiddle_fwd(float2* v, float2 w1) {
    float2 w2 = cmul(w1, w1);
    float2 wo = w1, we = w2;
    v[IDX16(1)] = cmul(v[IDX16(1)], wo);
    v[IDX16(2)] = cmul(v[IDX16(2)], we);
    #pragma unroll
    for (int p = 3; p < 16; p += 2) { wo = cmul(wo, w2); v[IDX16(p)] = cmul(v[IDX16(p)], wo); }
    #pragma unroll
    for (int p = 4; p < 16; p += 2) { we = cmul(we, w2); v[IDX16(p)] = cmul(v[IDX16(p)], we); }
}
// v[p] *= conj(w1^p), p=1..15 (natural slots)
__device__ __forceinline__ void twiddle_inv_nat(float2* v, float2 w1) {
    float2 w2 = cmul(w1, w1);
    float2 wo = w1, we = w2;
    v[1] = cmulc(v[1], wo);
    v[2] = cmulc(v[2], we);
    #pragma unroll
    for (int p = 3; p < 16; p += 2) { wo = cmul(wo, w2); v[p] = cmulc(v[p], wo); }
    #pragma unroll
    for (int p = 4; p < 16; p += 2) { we = cmul(we, w2); v[p] = cmulc(v[p], we); }
}
// v[IDX16(p)] *= conj(w1^p), p=1..15
__device__ __forceinline__ void twiddle_inv_idx(float2* v, float2 w1) {
    float2 w2 = cmul(w1, w1);
    float2 wo = w1, we = w2;
    v[IDX16(1)] = cmulc(v[IDX16(1)], wo);
    v[IDX16(2)] = cmulc(v[IDX16(2)], we);
    #pragma unroll
    for (int p = 3; p < 16; p += 2) { wo = cmul(wo, w2); v[IDX16(p)] = cmulc(v[IDX16(p)], wo); }
    #pragma unroll
    for (int p = 4; p < 16; p += 2) { we = cmul(we, w2); v[IDX16(p)] = cmulc(v[IDX16(p)], we); }
}

// ---------------------------------------------------------------------------
// prep: full Hermitian spectrum H[0..N) and twiddle table tw[0..N)
// (hot kernel now reads only tw[t] and tw[16*(t>>4)] as chain bases)
// ---------------------------------------------------------------------------
__global__ void prep_kernel(const float* __restrict__ wr, const float* __restrict__ wi,
                            float2* __restrict__ H, float2* __restrict__ tw) {
    int i = blockIdx.x * blockDim.x + threadIdx.x;
    if (i < N) {
        double ang = -2.0 * M_PI * (double)i / (double)N;
        tw[i] = make_float2((float)cos(ang), (float)sin(ang));
        float re, im;
        if (i <= N / 2) {
            re = wr[i];
            im = (i == N / 2) ? 0.0f : wi[i];
        } else {
            re = wr[N - i];
            im = -wi[N - i];
        }
        H[i] = make_float2(re, im);
    }
}

// ---------------------------------------------------------------------------
// One block = 2 rows packed as one complex sequence (z = x1 + i*x2; T is
// C-linear and real->real since H is Hermitian, so T(z) = y1 + i*y2).
// Radix-16 Stockham: stage (m): q=t, k=q%m, j=q/m;
//   d_p = sum_r a[q + r*256] w16^{rp};  b[k+(16j+p)m] = w_N^{jmp} d_p
// Stages m=1,16,256 forward; H-multiply fully in registers; m=1,16,256
// inverse (conjugated); single in-place swizzled LDS buffer.
// STRUCTURE IDENTICAL TO ROUND 0 (measured 174.7 us, 0 conflicts); the only
// change is twiddle gathers -> register chains.
// ---------------------------------------------------------------------------
__global__ __launch_bounds__(THREADS, 5) void fft_conv_kernel(
        const float* __restrict__ x, const float2* __restrict__ H,
        const float2* __restrict__ tw, const float* __restrict__ bias,
        float* __restrict__ out) {
    __shared__ float2 lds[N];   // 32 KB -> 5 blocks/CU if allocator permits
    const int t = threadIdx.x;
    const long base1 = (long)(2 * blockIdx.x) * N;
    const long base2 = base1 + N;

    // chain bases, issued early so they fly with the x loads:
    // w1 = W_N^t (coalesced), wb = W_N^{16j} = W_256^j (16-line broadcast)
    const float2 w1 = tw[t];
    const float2 wb = tw[16 * (t >> 4)];

    float2 v[16];

    // ---- load: fwd stage A reads pattern t+256r straight from global ----
    #pragma unroll
    for (int r = 0; r < 16; ++r) {
        v[r].x = x[base1 + t + 256 * r];
        v[r].y = x[base2 + t + 256 * r];
    }

    // ---- fwd A (m=1, k=0, j=t): twiddle w^(t*p), write 16t+p ----
    dft16<false>(v);
    twiddle_fwd(v, w1);                                     // was: tw[t*p] gathers
    #pragma unroll
    for (int p = 0; p < 16; ++p)
        lds[SWZ(16 * t + p)] = v[IDX16(p)];
    __syncthreads();

    // ---- fwd B (m=16): read t+256r, twiddle w^(16jp), write k+256j+16p ----
    #pragma unroll
    for (int r = 0; r < 16; ++r) v[r] = lds[SWZ(t + 256 * r)];
    __syncthreads();                                        // reads before in-place writes
    dft16<false>(v);
    {
        const int k = t & 15, j = t >> 4;
        twiddle_fwd(v, wb);                                 // was: tw[16*j*p] gathers
        #pragma unroll
        for (int p = 0; p < 16; ++p)
            lds[SWZ(k + 256 * j + 16 * p)] = v[IDX16(p)];
    }
    __syncthreads();

    // ---- fwd C (m=256, j=0, no twiddle) + pointwise H, all in registers ----
    #pragma unroll
    for (int r = 0; r < 16; ++r) v[r] = lds[SWZ(t + 256 * r)];
    __syncthreads();                                        // protect inv-A writes below
    dft16<false>(v);
    // slot q holds spectrum element at natural index t + 256*IDX16(q)
    #pragma unroll
    for (int q = 0; q < 16; ++q)
        v[q] = cmul(v[q], H[t + 256 * IDX16(q)]);

    // ---- inv A (m=1): input is IDX16-permuted in regs -> dft16_perm ----
    dft16_perm<true>(v);                                    // output X_p at slot p
    twiddle_inv_nat(v, w1);                                 // was: conj(tw[t*p]) gathers
    #pragma unroll
    for (int p = 0; p < 16; ++p)
        lds[SWZ(16 * t + p)] = v[p];
    __syncthreads();

    // ---- inv B (m=16) ----
    #pragma unroll
    for (int r = 0; r < 16; ++r) v[r] = lds[SWZ(t + 256 * r)];
    __syncthreads();
    dft16<true>(v);
    {
        const int k = t & 15, j = t >> 4;
        twiddle_inv_idx(v, wb);                             // was: conj(tw[16*j*p]) gathers
        #pragma unroll
        for (int p = 0; p < 16; ++p)
            lds[SWZ(k + 256 * j + 16 * p)] = v[IDX16(p)];
    }
    __syncthreads();

    // ---- inv C (m=256) + scale/bias epilogue straight to global ----
    #pragma unroll
    for (int r = 0; r < 16; ++r) v[r] = lds[SWZ(t + 256 * r)];
    dft16<true>(v);
    const float inv = 1.0f / (float)N;
    #pragma unroll
    for (int p = 0; p < 16; ++p) {
        float2 val = v[IDX16(p)];
        float bb = bias[t + 256 * p];
        out[base1 + t + 256 * p] = fmaf(val.x, inv, bb);
        out[base2 + t + 256 * p] = fmaf(val.y, inv, bb);
    }
}

// ---------------------------------------------------------------------------
extern "C" void kernel_launch(void* const* d_in, const int* in_sizes, int n_in,
                              void* d_out, int out_size, void* d_ws, size_t ws_size,
                              hipStream_t stream) {
    const float* x  = (const float*)d_in[0];   // (8192, 4096)
    const float* wr = (const float*)d_in[1];   // (2049,)
    const float* wi = (const float*)d_in[2];   // (2049,)
    const float* bs = (const float*)d_in[3];   // (4096,)
    float* out = (float*)d_out;                // (8192, 4096)

    float2* H  = (float2*)d_ws;                                       // 32 KB
    float2* tw = (float2*)((char*)d_ws + (size_t)N * sizeof(float2)); // 32 KB

    prep_kernel<<<dim3(N / THREADS), dim3(THREADS), 0, stream>>>(wr, wi, H, tw);
    fft_conv_kernel<<<dim3(BATCH / 2), dim3(THREADS), 0, stream>>>(x, H, tw, bs, out);
}

// Round 3
// 310.681 us; speedup vs baseline: 1.4257x; 1.4257x over previous
//
#include <hip/hip_runtime.h>
#include <math.h>

#define N 4096
#define THREADS 256
#define BATCH 8192

// XOR swizzle: bijection on [0,4096) making all three LDS access families
// (stride-256 reads, 16-contiguous writes, stride-16 writes) bank-minimal.
// MEASURED conflict-free in round 0 (SQ_LDS_BANK_CONFLICT == 0) -- do not touch.
#define SWZ(i) ((i) ^ (((i) >> 4) & 15))
// dft16 stores X_p at slot IDX16(p) (base-4 digit swap; involution)
#define IDX16(p) ((((p) & 3) << 2) | ((p) >> 2))

__device__ __forceinline__ float2 cmul(float2 a, float2 b) {
    return make_float2(fmaf(a.x, b.x, -(a.y * b.y)), fmaf(a.x, b.y, a.y * b.x));
}

// radix-4 butterfly at v[base + r*stride]; forward uses w4 = -i, inverse +i
template<bool INV>
__device__ __forceinline__ void dft4(float2* v, int base, int stride) {
    float2 a = v[base], b = v[base + stride], c = v[base + 2 * stride], d = v[base + 3 * stride];
    float2 t0 = make_float2(a.x + c.x, a.y + c.y);
    float2 t1 = make_float2(a.x - c.x, a.y - c.y);
    float2 t2 = make_float2(b.x + d.x, b.y + d.y);
    float2 t3 = make_float2(b.x - d.x, b.y - d.y);
    float2 j3 = INV ? make_float2(-t3.y, t3.x) : make_float2(t3.y, -t3.x);
    v[base]              = make_float2(t0.x + t2.x, t0.y + t2.y);
    v[base + stride]     = make_float2(t1.x + j3.x, t1.y + j3.y);
    v[base + 2 * stride] = make_float2(t0.x - t2.x, t0.y - t2.y);
    v[base + 3 * stride] = make_float2(t1.x - j3.x, t1.y - j3.y);
}

// internal W16^{n1*k2} twiddles; slot set is symmetric under n1<->k2 so this
// works for both dft16 and dft16_perm.
template<bool INV>
__device__ __forceinline__ void tw16(float2* v) {
    const float C1 = 0.9238795325112867f;
    const float S1 = 0.3826834323650898f;
    const float R2 = 0.7071067811865476f;
    const float s = INV ? 1.0f : -1.0f;
    const float2 W1 = make_float2(C1, s * S1);
    const float2 W2 = make_float2(R2, s * R2);
    const float2 W3 = make_float2(S1, s * C1);
    const float2 W6 = make_float2(-R2, s * R2);
    const float2 W9 = make_float2(-C1, -s * S1);
    v[5]  = cmul(v[5],  W1);
    v[9]  = cmul(v[9],  W2);
    v[13] = cmul(v[13], W3);
    v[6]  = cmul(v[6],  W2);
    { float2 z = v[10]; v[10] = INV ? make_float2(-z.y, z.x) : make_float2(z.y, -z.x); }  // W4 = -/+ i
    v[14] = cmul(v[14], W6);
    v[7]  = cmul(v[7],  W3);
    v[11] = cmul(v[11], W6);
    v[15] = cmul(v[15], W9);
}

// input sample n at v[n]; output X_p at v[IDX16(p)]
template<bool INV>
__device__ __forceinline__ void dft16(float2* v) {
    #pragma unroll
    for (int n1 = 0; n1 < 4; ++n1) dft4<INV>(v, n1, 4);
    tw16<INV>(v);
    #pragma unroll
    for (int k2 = 0; k2 < 4; ++k2) dft4<INV>(v, 4 * k2, 1);
}

// input sample n at v[IDX16(n)]; output X_p at v[p]
template<bool INV>
__device__ __forceinline__ void dft16_perm(float2* v) {
    #pragma unroll
    for (int n1 = 0; n1 < 4; ++n1) dft4<INV>(v, 4 * n1, 1);
    tw16<INV>(v);
    #pragma unroll
    for (int k2 = 0; k2 < 4; ++k2) dft4<INV>(v, k2, 4);
}

// ---------------------------------------------------------------------------
// prep: full Hermitian spectrum H[0..N), twiddle table tw[0..N), and the
// TRANSPOSED stage-A twiddle table twA[p*256+t] = W_N^{t*p}. For fixed p,
// consecutive lanes read consecutive entries -> one coalesced 512B/wave
// load instead of a stride-8p gather touching up to 64 cache lines.
// ---------------------------------------------------------------------------
__global__ void prep_kernel(const float* __restrict__ wr, const float* __restrict__ wi,
                            float2* __restrict__ H, float2* __restrict__ tw) {
    int i = blockIdx.x * blockDim.x + threadIdx.x;
    if (i < N) {
        double ang = -2.0 * M_PI * (double)i / (double)N;
        tw[i] = make_float2((float)cos(ang), (float)sin(ang));
        float re, im;
        if (i <= N / 2) {
            re = wr[i];
            im = (i == N / 2) ? 0.0f : wi[i];
        } else {
            re = wr[N - i];
            im = -wi[N - i];
        }
        H[i] = make_float2(re, im);
    }
}

__global__ void prep_twA_kernel(float2* __restrict__ twA) {
    int i = blockIdx.x * blockDim.x + threadIdx.x;   // i in [0, 4096)
    int p = i >> 8, t = i & 255;
    double ang = -2.0 * M_PI * (double)(t * p) / (double)N;
    twA[i] = make_float2((float)cos(ang), (float)sin(ang));
}

// ---------------------------------------------------------------------------
// One block = 2 rows packed as one complex sequence (z = x1 + i*x2; T is
// C-linear and real->real since H is Hermitian, so T(z) = y1 + i*y2).
// Radix-16 Stockham: stage (m): q=t, k=q%m, j=q/m;
//   d_p = sum_r a[q + r*256] w16^{rp};  b[k+(16j+p)m] = w_N^{jmp} d_p
// Stages m=1,16,256 forward; H-multiply fully in registers; m=1,16,256
// inverse (conjugated); single in-place swizzled LDS buffer.
// STRUCTURE IDENTICAL TO ROUND 0 (measured 174.7 us, VGPR 64, 0 conflicts);
// the ONLY change is stage-A twiddle reads tw[t*p] -> twA[p*256+t]
// (transposed table: coalesced instead of strided gather). No register
// chains (r1/r2 post-mortem: they spill v[16] to scratch -> +1GB HBM).
// ---------------------------------------------------------------------------
__global__ __launch_bounds__(THREADS, 4) void fft_conv_kernel(
        const float* __restrict__ x, const float2* __restrict__ H,
        const float2* __restrict__ tw, const float2* __restrict__ twA,
        const float* __restrict__ bias, float* __restrict__ out) {
    __shared__ float2 lds[N];   // 32 KB -> 4+ blocks/CU
    const int t = threadIdx.x;
    const long base1 = (long)(2 * blockIdx.x) * N;
    const long base2 = base1 + N;

    float2 v[16];

    // ---- load: fwd stage A reads pattern t+256r straight from global ----
    #pragma unroll
    for (int r = 0; r < 16; ++r) {
        v[r].x = x[base1 + t + 256 * r];
        v[r].y = x[base2 + t + 256 * r];
    }

    // ---- fwd A (m=1, k=0, j=t): twiddle w^(t*p), write 16t+p ----
    dft16<false>(v);
    #pragma unroll
    for (int p = 1; p < 16; ++p)
        v[IDX16(p)] = cmul(v[IDX16(p)], twA[p * 256 + t]);   // coalesced row read
    #pragma unroll
    for (int p = 0; p < 16; ++p)
        lds[SWZ(16 * t + p)] = v[IDX16(p)];
    __syncthreads();

    // ---- fwd B (m=16): read t+256r, twiddle w^(16jp), write k+256j+16p ----
    #pragma unroll
    for (int r = 0; r < 16; ++r) v[r] = lds[SWZ(t + 256 * r)];
    __syncthreads();                                        // reads before in-place writes
    dft16<false>(v);
    {
        const int k = t & 15, j = t >> 4;
        #pragma unroll
        for (int p = 1; p < 16; ++p)
            v[IDX16(p)] = cmul(v[IDX16(p)], tw[16 * j * p]); // 4-address broadcast, cheap
        #pragma unroll
        for (int p = 0; p < 16; ++p)
            lds[SWZ(k + 256 * j + 16 * p)] = v[IDX16(p)];
    }
    __syncthreads();

    // ---- fwd C (m=256, j=0, no twiddle) + pointwise H, all in registers ----
    #pragma unroll
    for (int r = 0; r < 16; ++r) v[r] = lds[SWZ(t + 256 * r)];
    __syncthreads();                                        // protect inv-A writes below
    dft16<false>(v);
    // slot q holds spectrum element at natural index t + 256*IDX16(q)
    #pragma unroll
    for (int q = 0; q < 16; ++q)
        v[q] = cmul(v[q], H[t + 256 * IDX16(q)]);

    // ---- inv A (m=1): input is IDX16-permuted in regs -> dft16_perm ----
    dft16_perm<true>(v);                                    // output X_p at slot p
    #pragma unroll
    for (int p = 1; p < 16; ++p) {
        float2 w = twA[p * 256 + t]; w.y = -w.y;             // conj, coalesced
        v[p] = cmul(v[p], w);
    }
    #pragma unroll
    for (int p = 0; p < 16; ++p)
        lds[SWZ(16 * t + p)] = v[p];
    __syncthreads();

    // ---- inv B (m=16) ----
    #pragma unroll
    for (int r = 0; r < 16; ++r) v[r] = lds[SWZ(t + 256 * r)];
    __syncthreads();
    dft16<true>(v);
    {
        const int k = t & 15, j = t >> 4;
        #pragma unroll
        for (int p = 1; p < 16; ++p) {
            float2 w = tw[16 * j * p]; w.y = -w.y;
            v[IDX16(p)] = cmul(v[IDX16(p)], w);
        }
        #pragma unroll
        for (int p = 0; p < 16; ++p)
            lds[SWZ(k + 256 * j + 16 * p)] = v[IDX16(p)];
    }
    __syncthreads();

    // ---- inv C (m=256) + scale/bias epilogue straight to global ----
    #pragma unroll
    for (int r = 0; r < 16; ++r) v[r] = lds[SWZ(t + 256 * r)];
    dft16<true>(v);
    const float inv = 1.0f / (float)N;
    #pragma unroll
    for (int p = 0; p < 16; ++p) {
        float2 val = v[IDX16(p)];
        float bb = bias[t + 256 * p];
        out[base1 + t + 256 * p] = fmaf(val.x, inv, bb);
        out[base2 + t + 256 * p] = fmaf(val.y, inv, bb);
    }
}

// ---------------------------------------------------------------------------
extern "C" void kernel_launch(void* const* d_in, const int* in_sizes, int n_in,
                              void* d_out, int out_size, void* d_ws, size_t ws_size,
                              hipStream_t stream) {
    const float* x  = (const float*)d_in[0];   // (8192, 4096)
    const float* wr = (const float*)d_in[1];   // (2049,)
    const float* wi = (const float*)d_in[2];   // (2049,)
    const float* bs = (const float*)d_in[3];   // (4096,)
    float* out = (float*)d_out;                // (8192, 4096)

    float2* H   = (float2*)d_ws;                                           // 32 KB
    float2* tw  = (float2*)((char*)d_ws + (size_t)N * sizeof(float2));     // 32 KB
    float2* twA = (float2*)((char*)d_ws + (size_t)2 * N * sizeof(float2)); // 32 KB

    prep_kernel<<<dim3(N / THREADS), dim3(THREADS), 0, stream>>>(wr, wi, H, tw);
    prep_twA_kernel<<<dim3(N / THREADS), dim3(THREADS), 0, stream>>>(twA);
    fft_conv_kernel<<<dim3(BATCH / 2), dim3(THREADS), 0, stream>>>(x, H, tw, twA, bs, out);
}

// Round 4
// 263.653 us; speedup vs baseline: 1.6800x; 1.1784x over previous
//
#include <hip/hip_runtime.h>
#include <math.h>

#define N 4096
#define THREADS 256
#define BATCH 8192

// XOR swizzle: bijection on [0,4096) making all three LDS access families
// (stride-256 reads, 16-contiguous writes, stride-16 writes) bank-minimal.
// MEASURED conflict-free (rounds 0 and 3: SQ_LDS_BANK_CONFLICT == 0) -- do not touch.
#define SWZ(i) ((i) ^ (((i) >> 4) & 15))
// dft16 stores X_p at slot IDX16(p) (base-4 digit swap; involution)
#define IDX16(p) ((((p) & 3) << 2) | ((p) >> 2))

__device__ __forceinline__ float2 cmul(float2 a, float2 b) {
    return make_float2(fmaf(a.x, b.x, -(a.y * b.y)), fmaf(a.x, b.y, a.y * b.x));
}

// radix-4 butterfly at v[base + r*stride]; forward uses w4 = -i, inverse +i
template<bool INV>
__device__ __forceinline__ void dft4(float2* v, int base, int stride) {
    float2 a = v[base], b = v[base + stride], c = v[base + 2 * stride], d = v[base + 3 * stride];
    float2 t0 = make_float2(a.x + c.x, a.y + c.y);
    float2 t1 = make_float2(a.x - c.x, a.y - c.y);
    float2 t2 = make_float2(b.x + d.x, b.y + d.y);
    float2 t3 = make_float2(b.x - d.x, b.y - d.y);
    float2 j3 = INV ? make_float2(-t3.y, t3.x) : make_float2(t3.y, -t3.x);
    v[base]              = make_float2(t0.x + t2.x, t0.y + t2.y);
    v[base + stride]     = make_float2(t1.x + j3.x, t1.y + j3.y);
    v[base + 2 * stride] = make_float2(t0.x - t2.x, t0.y - t2.y);
    v[base + 3 * stride] = make_float2(t1.x - j3.x, t1.y - j3.y);
}

// internal W16^{n1*k2} twiddles; slot set is symmetric under n1<->k2 so this
// works for both dft16 and dft16_perm.
template<bool INV>
__device__ __forceinline__ void tw16(float2* v) {
    const float C1 = 0.9238795325112867f;
    const float S1 = 0.3826834323650898f;
    const float R2 = 0.7071067811865476f;
    const float s = INV ? 1.0f : -1.0f;
    const float2 W1 = make_float2(C1, s * S1);
    const float2 W2 = make_float2(R2, s * R2);
    const float2 W3 = make_float2(S1, s * C1);
    const float2 W6 = make_float2(-R2, s * R2);
    const float2 W9 = make_float2(-C1, -s * S1);
    v[5]  = cmul(v[5],  W1);
    v[9]  = cmul(v[9],  W2);
    v[13] = cmul(v[13], W3);
    v[6]  = cmul(v[6],  W2);
    { float2 z = v[10]; v[10] = INV ? make_float2(-z.y, z.x) : make_float2(z.y, -z.x); }  // W4 = -/+ i
    v[14] = cmul(v[14], W6);
    v[7]  = cmul(v[7],  W3);
    v[11] = cmul(v[11], W6);
    v[15] = cmul(v[15], W9);
}

// input sample n at v[n]; output X_p at v[IDX16(p)]
template<bool INV>
__device__ __forceinline__ void dft16(float2* v) {
    #pragma unroll
    for (int n1 = 0; n1 < 4; ++n1) dft4<INV>(v, n1, 4);
    tw16<INV>(v);
    #pragma unroll
    for (int k2 = 0; k2 < 4; ++k2) dft4<INV>(v, 4 * k2, 1);
}

// input sample n at v[IDX16(n)]; output X_p at v[p]
template<bool INV>
__device__ __forceinline__ void dft16_perm(float2* v) {
    #pragma unroll
    for (int n1 = 0; n1 < 4; ++n1) dft4<INV>(v, 4 * n1, 1);
    tw16<INV>(v);
    #pragma unroll
    for (int k2 = 0; k2 < 4; ++k2) dft4<INV>(v, k2, 4);
}

// ---------------------------------------------------------------------------
// prep: full Hermitian spectrum H[0..N), twiddle table tw[0..N), and the
// TRANSPOSED stage-A twiddle table twA[p*256+t] = W_N^{t*p} (coalesced reads;
// measured win in round 3).
// ---------------------------------------------------------------------------
__global__ void prep_kernel(const float* __restrict__ wr, const float* __restrict__ wi,
                            float2* __restrict__ H, float2* __restrict__ tw) {
    int i = blockIdx.x * blockDim.x + threadIdx.x;
    if (i < N) {
        double ang = -2.0 * M_PI * (double)i / (double)N;
        tw[i] = make_float2((float)cos(ang), (float)sin(ang));
        float re, im;
        if (i <= N / 2) {
            re = wr[i];
            im = (i == N / 2) ? 0.0f : wi[i];
        } else {
            re = wr[N - i];
            im = -wi[N - i];
        }
        H[i] = make_float2(re, im);
    }
}

__global__ void prep_twA_kernel(float2* __restrict__ twA) {
    int i = blockIdx.x * blockDim.x + threadIdx.x;   // i in [0, 4096)
    int p = i >> 8, t = i & 255;
    double ang = -2.0 * M_PI * (double)(t * p) / (double)N;
    twA[i] = make_float2((float)cos(ang), (float)sin(ang));
}

// ---------------------------------------------------------------------------
// One block = 4 rows = TWO independent complex sequences (za = r0 + i*r1,
// zb = r2 + i*r3), processed in lockstep by the same 256 threads.
// Rationale (round-3 post-mortem): the kernel is latency-bound with waves
// phase-locked at barriers (VALU and LDS pipes alternate idle). Two
// independent per-thread streams let seq-B's ds_reads/VALU overlap seq-A's
// (lgkmcnt-counted by the compiler), halve barrier count per row, and share
// every twiddle/H/bias operand load between the two sequences.
// Structure per sequence IDENTICAL to round 3 (measured 151 us, 0 conflicts).
// LDS 64 KB -> 2 blocks/CU; 2 blocks x 4 waves x 2 streams = 16 streams/CU.
// launch_bounds(256,2): VGPR cap 256 -- no spill pressure (r1/r2 lesson:
// verify WRITE_SIZE stays ~172 MB).
// ---------------------------------------------------------------------------
__global__ __launch_bounds__(THREADS, 2) void fft_conv_kernel(
        const float* __restrict__ x, const float2* __restrict__ H,
        const float2* __restrict__ tw, const float2* __restrict__ twA,
        const float* __restrict__ bias, float* __restrict__ out) {
    __shared__ float2 lds[2 * N];   // 64 KB
    float2* __restrict__ ldsA = lds;
    float2* __restrict__ ldsB = lds + N;
    const int t = threadIdx.x;
    const long base1 = (long)(4 * blockIdx.x) * N;  // row 4b
    const long base2 = base1 + N;                   // row 4b+1
    const long base3 = base1 + 2 * N;               // row 4b+2
    const long base4 = base1 + 3 * N;               // row 4b+3

    float2 va[16], vb[16];

    // ---- load both sequences: pattern t+256r, coalesced ----
    #pragma unroll
    for (int r = 0; r < 16; ++r) {
        va[r].x = x[base1 + t + 256 * r];
        va[r].y = x[base2 + t + 256 * r];
    }
    #pragma unroll
    for (int r = 0; r < 16; ++r) {
        vb[r].x = x[base3 + t + 256 * r];
        vb[r].y = x[base4 + t + 256 * r];
    }

    // ---- fwd A (m=1): twiddle w^(t*p) from transposed table, shared ----
    dft16<false>(va);
    dft16<false>(vb);
    #pragma unroll
    for (int p = 1; p < 16; ++p) {
        float2 w = twA[p * 256 + t];                 // coalesced, one load, two uses
        va[IDX16(p)] = cmul(va[IDX16(p)], w);
        vb[IDX16(p)] = cmul(vb[IDX16(p)], w);
    }
    #pragma unroll
    for (int p = 0; p < 16; ++p) ldsA[SWZ(16 * t + p)] = va[IDX16(p)];
    #pragma unroll
    for (int p = 0; p < 16; ++p) ldsB[SWZ(16 * t + p)] = vb[IDX16(p)];
    __syncthreads();

    // ---- fwd B (m=16): read t+256r, twiddle w^(16jp), write k+256j+16p ----
    #pragma unroll
    for (int r = 0; r < 16; ++r) va[r] = ldsA[SWZ(t + 256 * r)];
    #pragma unroll
    for (int r = 0; r < 16; ++r) vb[r] = ldsB[SWZ(t + 256 * r)];
    __syncthreads();                                // reads before in-place writes
    dft16<false>(va);
    dft16<false>(vb);
    {
        const int k = t & 15, j = t >> 4;
        #pragma unroll
        for (int p = 1; p < 16; ++p) {
            float2 w = tw[16 * j * p];               // 4-address broadcast, shared
            va[IDX16(p)] = cmul(va[IDX16(p)], w);
            vb[IDX16(p)] = cmul(vb[IDX16(p)], w);
        }
        #pragma unroll
        for (int p = 0; p < 16; ++p) ldsA[SWZ(k + 256 * j + 16 * p)] = va[IDX16(p)];
        #pragma unroll
        for (int p = 0; p < 16; ++p) ldsB[SWZ(k + 256 * j + 16 * p)] = vb[IDX16(p)];
    }
    __syncthreads();

    // ---- fwd C (m=256, no twiddle) + pointwise H, all in registers ----
    #pragma unroll
    for (int r = 0; r < 16; ++r) va[r] = ldsA[SWZ(t + 256 * r)];
    #pragma unroll
    for (int r = 0; r < 16; ++r) vb[r] = ldsB[SWZ(t + 256 * r)];
    __syncthreads();                                // protect inv-A writes below
    dft16<false>(va);
    dft16<false>(vb);
    // slot q holds spectrum element at natural index t + 256*IDX16(q)
    #pragma unroll
    for (int q = 0; q < 16; ++q) {
        float2 h = H[t + 256 * IDX16(q)];            // coalesced, shared
        va[q] = cmul(va[q], h);
        vb[q] = cmul(vb[q], h);
    }

    // ---- inv A (m=1): input IDX16-permuted in regs -> dft16_perm ----
    dft16_perm<true>(va);                           // output X_p at slot p
    dft16_perm<true>(vb);
    #pragma unroll
    for (int p = 1; p < 16; ++p) {
        float2 w = twA[p * 256 + t]; w.y = -w.y;     // conj, coalesced, shared
        va[p] = cmul(va[p], w);
        vb[p] = cmul(vb[p], w);
    }
    #pragma unroll
    for (int p = 0; p < 16; ++p) ldsA[SWZ(16 * t + p)] = va[p];
    #pragma unroll
    for (int p = 0; p < 16; ++p) ldsB[SWZ(16 * t + p)] = vb[p];
    __syncthreads();

    // ---- inv B (m=16) ----
    #pragma unroll
    for (int r = 0; r < 16; ++r) va[r] = ldsA[SWZ(t + 256 * r)];
    #pragma unroll
    for (int r = 0; r < 16; ++r) vb[r] = ldsB[SWZ(t + 256 * r)];
    __syncthreads();
    dft16<true>(va);
    dft16<true>(vb);
    {
        const int k = t & 15, j = t >> 4;
        #pragma unroll
        for (int p = 1; p < 16; ++p) {
            float2 w = tw[16 * j * p]; w.y = -w.y;
            va[IDX16(p)] = cmul(va[IDX16(p)], w);
            vb[IDX16(p)] = cmul(vb[IDX16(p)], w);
        }
        #pragma unroll
        for (int p = 0; p < 16; ++p) ldsA[SWZ(k + 256 * j + 16 * p)] = va[IDX16(p)];
        #pragma unroll
        for (int p = 0; p < 16; ++p) ldsB[SWZ(k + 256 * j + 16 * p)] = vb[IDX16(p)];
    }
    __syncthreads();

    // ---- inv C (m=256) + scale/bias epilogue straight to global ----
    #pragma unroll
    for (int r = 0; r < 16; ++r) va[r] = ldsA[SWZ(t + 256 * r)];
    #pragma unroll
    for (int r = 0; r < 16; ++r) vb[r] = ldsB[SWZ(t + 256 * r)];
    dft16<true>(va);
    dft16<true>(vb);
    const float inv = 1.0f / (float)N;
    #pragma unroll
    for (int p = 0; p < 16; ++p) {
        float2 a = va[IDX16(p)];
        float2 b = vb[IDX16(p)];
        float bb = bias[t + 256 * p];                // one load, four uses
        out[base1 + t + 256 * p] = fmaf(a.x, inv, bb);
        out[base2 + t + 256 * p] = fmaf(a.y, inv, bb);
        out[base3 + t + 256 * p] = fmaf(b.x, inv, bb);
        out[base4 + t + 256 * p] = fmaf(b.y, inv, bb);
    }
}

// ---------------------------------------------------------------------------
extern "C" void kernel_launch(void* const* d_in, const int* in_sizes, int n_in,
                              void* d_out, int out_size, void* d_ws, size_t ws_size,
                              hipStream_t stream) {
    const float* x  = (const float*)d_in[0];   // (8192, 4096)
    const float* wr = (const float*)d_in[1];   // (2049,)
    const float* wi = (const float*)d_in[2];   // (2049,)
    const float* bs = (const float*)d_in[3];   // (4096,)
    float* out = (float*)d_out;                // (8192, 4096)

    float2* H   = (float2*)d_ws;                                           // 32 KB
    float2* tw  = (float2*)((char*)d_ws + (size_t)N * sizeof(float2));     // 32 KB
    float2* twA = (float2*)((char*)d_ws + (size_t)2 * N * sizeof(float2)); // 32 KB

    prep_kernel<<<dim3(N / THREADS), dim3(THREADS), 0, stream>>>(wr, wi, H, tw);
    prep_twA_kernel<<<dim3(N / THREADS), dim3(THREADS), 0, stream>>>(twA);
    fft_conv_kernel<<<dim3(BATCH / 4), dim3(THREADS), 0, stream>>>(x, H, tw, twA, bs, out);
}